// Round 1
// baseline (542.557 us; speedup 1.0000x reference)
//
#include <hip/hip_runtime.h>
#include <stdint.h>

#define H_DIM 2048
#define E_NUM 8
#define D_DIM 2048
#define NTOK 4096

typedef __bf16 bf16x8 __attribute__((ext_vector_type(8)));
typedef float f32x4 __attribute__((ext_vector_type(4)));

__device__ __forceinline__ unsigned short f2bf(float f) {
    union { float f; uint32_t u; } c; c.f = f;
    uint32_t r = (c.u + 0x7FFFu + ((c.u >> 16) & 1u)) >> 16;
    return (unsigned short)r;
}
__device__ __forceinline__ float bf2f(unsigned short h) {
    union { float f; uint32_t u; } c; c.u = ((uint32_t)h) << 16;
    return c.f;
}

// async global->LDS, 16B/lane; LDS dest = wave-uniform base + lane*16.
__device__ __forceinline__ void gl_lds16(const unsigned short* g, unsigned short* l) {
    __builtin_amdgcn_global_load_lds(
        (const __attribute__((address_space(1))) unsigned int*)g,
        (__attribute__((address_space(3))) unsigned int*)l, 16, 0, 0);
}

// ------- K1: router, wave-per-token, fused x -> bf16 conversion -------------
__global__ __launch_bounds__(256) void router_cvt_kernel(
    const float* __restrict__ x, const float* __restrict__ rw,
    const float* __restrict__ rb, int* __restrict__ counts,
    uint32_t* __restrict__ tok, float* __restrict__ gate,
    unsigned short* __restrict__ xb) {
    int t = (blockIdx.x * 256 + threadIdx.x) >> 6;  // token = global wave id
    int lane = threadIdx.x & 63;
    const float* xr = x + (size_t)t * H_DIM;
    unsigned short* xo = xb + (size_t)t * H_DIM;
    float p[E_NUM];
#pragma unroll
    for (int e = 0; e < E_NUM; e++) p[e] = 0.f;
#pragma unroll
    for (int pass = 0; pass < H_DIM / 256; pass++) {
        int h = pass * 256 + lane * 4;
        float4 v = *(const float4*)(xr + h);
        ushort4 o;
        o.x = f2bf(v.x); o.y = f2bf(v.y); o.z = f2bf(v.z); o.w = f2bf(v.w);
        *(ushort4*)(xo + h) = o;
        const float* r0 = rw + (size_t)h * E_NUM;
#pragma unroll
        for (int e = 0; e < E_NUM; e++)
            p[e] += v.x * r0[e] + v.y * r0[e + 8] + v.z * r0[e + 16] + v.w * r0[e + 24];
    }
#pragma unroll
    for (int e = 0; e < E_NUM; e++) {
#pragma unroll
        for (int off = 1; off < 64; off <<= 1) p[e] += __shfl_xor(p[e], off, 64);
    }
    if (lane == 0) {
        float l[E_NUM];
#pragma unroll
        for (int e = 0; e < E_NUM; e++) l[e] = p[e] + rb[e];
        int e0 = 0;
#pragma unroll
        for (int e = 1; e < E_NUM; e++) if (l[e] > l[e0]) e0 = e;
        int e1 = (e0 == 0) ? 1 : 0;
#pragma unroll
        for (int e = 0; e < E_NUM; e++) if (e != e0 && l[e] > l[e1]) e1 = e;
        float g0 = 1.f / (1.f + __expf(l[e1] - l[e0]));
        float g1 = 1.f - g0;
        int p0 = atomicAdd(&counts[e0], 1);
        tok[e0 * NTOK + p0] = (uint32_t)t;
        gate[e0 * NTOK + p0] = g0;
        int p1 = atomicAdd(&counts[e1], 1);
        tok[e1 * NTOK + p1] = (uint32_t)t | (1u << 16);
        gate[e1 * NTOK + p1] = g1;
    }
}

// ------- K2: fused fp32 [K][N] -> bf16 [N][K] transpose for ew + ow ---------
__global__ __launch_bounds__(256) void transpose_cvt_kernel(
    const float* __restrict__ ew, const float* __restrict__ ow,
    unsigned short* __restrict__ ewT) {
    __shared__ unsigned short t[64][136];       // [n][k], +8 pad
    int z = blockIdx.z;
    const float* s = (z < 8) ? (ew + (size_t)z * H_DIM * D_DIM) : ow;
    unsigned short* d = ewT + (size_t)z * H_DIM * D_DIM;
    int n0 = blockIdx.x * 64, k0 = blockIdx.y * 128;
    int tid = threadIdx.x;
    int rr = tid >> 4;          // 0..15
    int c4 = (tid & 15) * 4;    // n offset (floats) in read phase
#pragma unroll
    for (int p = 0; p < 8; p++) {
        int k = p * 16 + rr;
        float4 v = *(const float4*)(s + (size_t)(k0 + k) * D_DIM + n0 + c4);
        t[c4 + 0][k] = f2bf(v.x);
        t[c4 + 1][k] = f2bf(v.y);
        t[c4 + 2][k] = f2bf(v.z);
        t[c4 + 3][k] = f2bf(v.w);
    }
    __syncthreads();
    int kc = (tid & 15) * 8;    // k offset in write phase: 16 lanes x 16B
#pragma unroll
    for (int p = 0; p < 4; p++) {
        int n = p * 16 + rr;
        uint4 v = *(const uint4*)&t[n][kc];
        *(uint4*)(d + (size_t)(n0 + n) * H_DIM + k0 + kc) = v;
    }
}

// ------- K3/K5: 8-phase double-buffered 128x256xBK64 GEMM (T2+T3+T4+T5) -----
// 512 threads = 8 waves (2M x 4N), 64x64 per wave, mfma 16x16x32 bf16.
// LDS: A[2][128][64] + B[2][256][64] bf16, chunk-XOR swizzle (kc ^ (row&7)).
// Staging via global_load_lds (linear dest, inverse-swizzled per-lane source).
// Per K-tile: 4 phases {ds_read || stage 1 unit -> bar -> lgkm0 -> 8 MFMA -> bar},
// counted vmcnt(4) once per tile (5 stage-units x 2 loads in flight max).

#define GBAR() __builtin_amdgcn_s_barrier()
#define LGKM0() do { asm volatile("s_waitcnt lgkmcnt(0)" ::: "memory"); \
                     __builtin_amdgcn_sched_barrier(0); } while (0)
#define VMW(N) asm volatile("s_waitcnt vmcnt(" #N ")" ::: "memory")

template <int MOE>
__global__ __launch_bounds__(512, 2) void gemm8p_kernel(
    const unsigned short* __restrict__ Amat,  // xb or comb  [rows][2048] bf16
    const unsigned short* __restrict__ Bmat,  // ewT (per-e) or owT [n][2048] bf16
    const float* __restrict__ bias,           // eb or ob
    const int* __restrict__ counts,
    const uint32_t* __restrict__ tok,
    const float* __restrict__ gate,
    unsigned short* __restrict__ Ybf,         // MOE: [NTOK][2][D] bf16
    float* __restrict__ outF) {               // dense: [NTOK][D] fp32
    constexpr int KD = 2048;
    constexpr int NT = KD / 64;               // 32 K-tiles

    __shared__ unsigned short sA[2][128 * 64];
    __shared__ unsigned short sB[2][256 * 64];
    __shared__ uint32_t tok_s[128];
    __shared__ float gate_s[128];

    const int e = MOE ? blockIdx.z : 0;
    const int cnt = MOE ? counts[e] : NTOK;
    const int m0 = blockIdx.y * 128;
    if (MOE && m0 >= cnt) return;
    const int n0 = blockIdx.x * 256;
    const int tid = threadIdx.x;

    if (MOE) {
        if (tid < 128) {
            int idx = m0 + tid;
            uint32_t tk = 0; float g = 0.f;
            if (idx < cnt) { tk = tok[e * NTOK + idx]; g = gate[e * NTOK + idx]; }
            tok_s[tid] = tk; gate_s[tid] = g;
        }
        __syncthreads();
    }

    const unsigned short* Bp = Bmat + (size_t)e * D_DIM * KD;

    // staging: thread covers rows (l*64 + tid>>3), phys chunk tid&7; source
    // chunk pre-swizzled so logical chunk kc lands at phys kc^(row&7).
    const int rr = tid >> 3;
    const int swz = ((tid & 7) ^ (rr & 7)) * 8;
    uint32_t aOff[2], bOff[4];
#pragma unroll
    for (int l = 0; l < 2; l++) {
        int r = l * 64 + rr;
        uint32_t arow = MOE ? (tok_s[r] & 0xFFFFu) : (uint32_t)(m0 + r);
        aOff[l] = arow * (uint32_t)KD + swz;
    }
#pragma unroll
    for (int h = 0; h < 2; h++)
#pragma unroll
        for (int l = 0; l < 2; l++) {
            int r = h * 128 + l * 64 + rr;
            bOff[h * 2 + l] = (uint32_t)(n0 + r) * (uint32_t)KD + swz;
        }

    const int lane = tid & 63;
    const int wave = tid >> 6;
    const int wm = wave >> 2;   // 0..1 : M strip of 64
    const int wn = wave & 3;    // 0..3 : N strip of 64
    const int row16 = lane & 15;
    const int quad = lane >> 4;
    const int baseA = (wm * 64 + row16) * 64;
    const int baseB = (wn * 64 + row16) * 64;
    const int xo0 = ((quad) ^ (lane & 7)) * 8;       // ksub 0, swizzled chunk
    const int xo1 = ((4 + quad) ^ (lane & 7)) * 8;   // ksub 1
    const int wbase = wave * 512;                    // lane0 LDS offs per step

#define STG_A(BUF, T) do { \
        gl_lds16(Amat + aOff[0] + (T) * 64, &sA[BUF][wbase]); \
        gl_lds16(Amat + aOff[1] + (T) * 64, &sA[BUF][4096 + wbase]); } while (0)
#define STG_B(BUF, HH, T) do { \
        gl_lds16(Bp + bOff[(HH) * 2 + 0] + (T) * 64, &sB[BUF][(HH) * 8192 + wbase]); \
        gl_lds16(Bp + bOff[(HH) * 2 + 1] + (T) * 64, &sB[BUF][(HH) * 8192 + 4096 + wbase]); } while (0)

    bf16x8 aLo[2][2], aHi[2][2], bLo[2][2], bHi[2][2];
    f32x4 acc[4][4];
#pragma unroll
    for (int i = 0; i < 4; i++)
#pragma unroll
        for (int j = 0; j < 4; j++) acc[i][j] = (f32x4)(0.f);

#define LOADA(DST, FB, BUF) do { _Pragma("unroll") \
        for (int f_ = 0; f_ < 2; f_++) { \
            DST[f_][0] = *(const bf16x8*)&sA[BUF][baseA + ((FB) + f_) * 1024 + xo0]; \
            DST[f_][1] = *(const bf16x8*)&sA[BUF][baseA + ((FB) + f_) * 1024 + xo1]; } } while (0)
#define LOADB(DST, FB, BUF) do { _Pragma("unroll") \
        for (int c_ = 0; c_ < 2; c_++) { \
            DST[c_][0] = *(const bf16x8*)&sB[BUF][baseB + ((FB) + c_) * 1024 + xo0]; \
            DST[c_][1] = *(const bf16x8*)&sB[BUF][baseB + ((FB) + c_) * 1024 + xo1]; } } while (0)
#define MFMAQ(AF, BF, FR, FC) do { _Pragma("unroll") \
        for (int s_ = 0; s_ < 2; s_++) { _Pragma("unroll") \
            for (int f_ = 0; f_ < 2; f_++) { _Pragma("unroll") \
                for (int c_ = 0; c_ < 2; c_++) \
                    acc[(FR) + f_][(FC) + c_] = __builtin_amdgcn_mfma_f32_16x16x32_bf16( \
                        AF[f_][s_], BF[c_][s_], acc[(FR) + f_][(FC) + c_], 0, 0, 0); } } } while (0)

// Per-tile 4 phases. Stage slots: P1: Bh1(T+1) -> other buf (region free since
// prev tile P2); P3: Bh0(T+2) -> this buf (free after this P2); P4: A(T+2) ->
// this buf (free after this P3). vmcnt(4) at P4 => tile T+1 (oldest 6 loads)
// landed before next tile's reads; 2 units (4 loads) stay in flight.
#define TILE(BC, BN_, T, S1, S3, S4, VMLINE) do { \
        /* P1 */ \
        LOADA(aLo, 0, BC); LOADB(bLo, 0, BC); \
        if (S1) STG_B(BN_, 1, (T) + 1); \
        GBAR(); LGKM0(); \
        __builtin_amdgcn_s_setprio(1); MFMAQ(aLo, bLo, 0, 0); __builtin_amdgcn_s_setprio(0); \
        GBAR(); \
        /* P2 */ \
        LOADB(bHi, 2, BC); \
        GBAR(); LGKM0(); \
        __builtin_amdgcn_s_setprio(1); MFMAQ(aLo, bHi, 0, 2); __builtin_amdgcn_s_setprio(0); \
        GBAR(); \
        /* P3 */ \
        LOADA(aHi, 2, BC); \
        if (S3) STG_B(BC, 0, (T) + 2); \
        GBAR(); LGKM0(); \
        __builtin_amdgcn_s_setprio(1); MFMAQ(aHi, bLo, 2, 0); __builtin_amdgcn_s_setprio(0); \
        GBAR(); \
        /* P4 */ \
        if (S4) STG_A(BC, (T) + 2); \
        VMLINE; \
        GBAR(); \
        __builtin_amdgcn_s_setprio(1); MFMAQ(aHi, bHi, 2, 2); __builtin_amdgcn_s_setprio(0); \
        GBAR(); } while (0)

    // prologue: tile0 fully staged + first 2 units of tile1 in flight
    STG_B(0, 0, 0); STG_B(0, 1, 0); STG_A(0, 0);
    STG_B(1, 0, 1); STG_A(1, 1);
    VMW(4);
    GBAR();

    int t0 = 0;
#pragma unroll 1
    for (int tp = 0; tp < NT / 2 - 1; ++tp, t0 += 2) {
        TILE(0, 1, t0, 1, 1, 1, VMW(4));
        TILE(1, 0, t0 + 1, 1, 1, 1, VMW(4));
    }
    // tail: tiles NT-2 (buf0) and NT-1 (buf1)
    TILE(0, 1, NT - 2, 1, 0, 0, VMW(0));
    TILE(1, 0, NT - 1, 0, 0, 0, (void)0);

    // epilogue
    if (MOE) {
#pragma unroll
        for (int f = 0; f < 4; f++) {
            const int rb = wm * 64 + f * 16 + quad * 4;
#pragma unroll
            for (int c = 0; c < 4; c++) {
                const int n = n0 + wn * 64 + c * 16 + row16;
                const float bv = bias[e * D_DIM + n];
#pragma unroll
                for (int r = 0; r < 4; r++) {
                    const int lrow = rb + r;
                    if (m0 + lrow < cnt) {
                        const uint32_t tk = tok_s[lrow];
                        const float g = gate_s[lrow];
                        float v = acc[f][c][r] + bv;
                        float q = 0.7978845608028654f * (v + 0.044715f * v * v * v);
                        float gl = v / (1.f + __expf(-2.f * q));
                        Ybf[((size_t)(tk & 0xFFFFu) * 2 + ((tk >> 16) & 1)) * D_DIM + n] =
                            f2bf(g * gl);
                    }
                }
            }
        }
    } else {
#pragma unroll
        for (int f = 0; f < 4; f++) {
            const int rb = m0 + wm * 64 + f * 16 + quad * 4;
#pragma unroll
            for (int c = 0; c < 4; c++) {
                const int n = n0 + wn * 64 + c * 16 + row16;
                const float bv = bias[n];
#pragma unroll
                for (int r = 0; r < 4; r++)
                    outF[(size_t)(rb + r) * D_DIM + n] = acc[f][c][r] + bv;
            }
        }
    }
#undef STG_A
#undef STG_B
#undef LOADA
#undef LOADB
#undef MFMAQ
#undef TILE
}

// ------- K4: combine slot0+slot1 -> bf16 combined ---------------------------
__global__ __launch_bounds__(256) void combine_kernel(
    const unsigned short* __restrict__ Y, unsigned short* __restrict__ comb) {
    int i = blockIdx.x * 256 + threadIdx.x;  // over NTOK*D/8
    int t = i >> 8;
    int dc = (i & 255) * 8;
    uint4 u0 = *(const uint4*)(Y + (size_t)t * 2 * D_DIM + dc);
    uint4 u1 = *(const uint4*)(Y + ((size_t)t * 2 + 1) * D_DIM + dc);
    uint4 o;
    uint32_t* po = (uint32_t*)&o;
    const uint32_t* p0 = (const uint32_t*)&u0;
    const uint32_t* p1 = (const uint32_t*)&u1;
#pragma unroll
    for (int k = 0; k < 4; k++) {
        uint32_t a = p0[k], b = p1[k];
        float s0 = bf2f((unsigned short)(a & 0xFFFF)) + bf2f((unsigned short)(b & 0xFFFF));
        float s1 = bf2f((unsigned short)(a >> 16)) + bf2f((unsigned short)(b >> 16));
        po[k] = (uint32_t)f2bf(s0) | ((uint32_t)f2bf(s1) << 16);
    }
    *(uint4*)(comb + (size_t)t * D_DIM + dc) = o;
}

extern "C" void kernel_launch(void* const* d_in, const int* in_sizes, int n_in,
                              void* d_out, int out_size, void* d_ws, size_t ws_size,
                              hipStream_t stream) {
    const float* x        = (const float*)d_in[0];  // [4096, 2048]
    const float* router_w = (const float*)d_in[1];  // [2048, 8]
    const float* router_b = (const float*)d_in[2];  // [8]
    const float* expert_w = (const float*)d_in[3];  // [8, 2048, 2048]
    const float* expert_b = (const float*)d_in[4];  // [8, 2048]
    const float* out_w    = (const float*)d_in[5];  // [2048, 2048]
    const float* out_b    = (const float*)d_in[6];  // [2048]
    float* out = (float*)d_out;                     // [4096, 2048]

    char* w = (char*)d_ws;
    int* counts = (int*)w;                          // @0
    uint32_t* tok = (uint32_t*)(w + 1024);
    float* gate = (float*)(w + 1024 + E_NUM * NTOK * 4);
    size_t off = 1024 + (size_t)2 * E_NUM * NTOK * 4;
    unsigned short* xb = (unsigned short*)(w + off);
    off += (size_t)NTOK * H_DIM * 2;
    unsigned short* ewT = (unsigned short*)(w + off);     // [8][D][H]
    off += (size_t)E_NUM * H_DIM * D_DIM * 2;
    unsigned short* owT = (unsigned short*)(w + off);     // contiguous after ewT
    off += (size_t)D_DIM * D_DIM * 2;
    unsigned short* Y = (unsigned short*)(w + off);
    off += (size_t)NTOK * 2 * D_DIM * 2;
    unsigned short* comb = (unsigned short*)(w + off);

    hipMemsetAsync(d_ws, 0, 1024, stream);
    router_cvt_kernel<<<NTOK / 4, 256, 0, stream>>>(x, router_w, router_b,
                                                    counts, tok, gate, xb);
    transpose_cvt_kernel<<<dim3(32, 16, 9), 256, 0, stream>>>(expert_w, out_w, ewT);
    gemm8p_kernel<1><<<dim3(8, 32, 8), 512, 0, stream>>>(
        xb, ewT, expert_b, counts, tok, gate, Y, nullptr);
    combine_kernel<<<NTOK * D_DIM / 8 / 256, 256, 0, stream>>>(Y, comb);
    gemm8p_kernel<0><<<dim3(8, 32, 1), 512, 0, stream>>>(
        comb, owT, out_b, nullptr, nullptr, nullptr, nullptr, out);
}